// Round 1
// baseline (25.124 us; speedup 1.0000x reference)
//
#include <hip/hip_runtime.h>

// Reference collapse:
//   softmax is over the QUERY axis (dim=1 of scores[b,q,k]), so
//   sum_q attn[b,q,k] == 1  for every (b,k).  Hence
//   context.mean(axis=0) = mean_k V[k,b,:] = xbar @ Wv.T + bv,
//   out[b,h] = xbar[b,h] + sum_j xbar[b,j]*Wv[h,j] + bv[h],
//   with xbar = x.mean(axis=0).  Exact math, not an approximation.
// Only x (64 MiB) must be streamed from HBM; the rest is a tiny matvec.

constexpr int S = 1024;
constexpr int B = 16;
constexpr int H = 1024;
constexpr int C = B * H;            // 16384 columns when x is viewed [S][B*H]
constexpr int SPLITS = 32;          // S-axis split for kernel 1
constexpr int SCHUNK = S / SPLITS;  // 32 rows per block

// --- K1 (deterministic path): partial column sums, float4 across columns.
// grid (C/4/256, SPLITS) = (16, 32), block 256.
__global__ void k_colsum(const float4* __restrict__ x4, float4* __restrict__ part4) {
    const int c4 = blockIdx.x * blockDim.x + threadIdx.x;   // [0, C/4)
    const int split = blockIdx.y;
    const float4* p = x4 + (size_t)split * SCHUNK * (C / 4) + c4;
    float4 a = make_float4(0.f, 0.f, 0.f, 0.f);
#pragma unroll
    for (int i = 0; i < SCHUNK; ++i) {
        float4 v = p[(size_t)i * (C / 4)];
        a.x += v.x; a.y += v.y; a.z += v.z; a.w += v.w;
    }
    part4[(size_t)split * (C / 4) + c4] = a;
}

// --- K1 (fallback path, ws too small): atomic accumulation into xsum[C].
__global__ void k_colsum_atomic(const float* __restrict__ x, float* __restrict__ xsum) {
    const int c = blockIdx.x * blockDim.x + threadIdx.x;    // grid.x = C/256
    const int split = blockIdx.y;
    const float* p = x + (size_t)split * SCHUNK * C + c;
    float a = 0.f;
#pragma unroll 8
    for (int i = 0; i < SCHUNK; ++i) a += p[(size_t)i * C];
    atomicAdd(&xsum[c], a);
}

// --- K1.5: fold SPLITS partial rows -> xsum[C] (raw sums over S, unscaled).
// grid C/256 = 64, block 256.
__global__ void k_reduce(const float* __restrict__ part, float* __restrict__ xsum) {
    const int c = blockIdx.x * blockDim.x + threadIdx.x;
    float a = 0.f;
#pragma unroll
    for (int t = 0; t < SPLITS; ++t) a += part[(size_t)t * C + c];
    xsum[c] = a;
}

// --- K2: one wave per output element.
// out[b*H+h] = (xsum[b*H+h] + sum_j xsum[b*H+j]*Wv[h*H+j]) / S + bv[h]
// grid 4096, block 256 (4 waves/block) -> 16384 waves.
__global__ void k_out(const float* __restrict__ xsum, const float* __restrict__ Wv,
                      const float* __restrict__ bv, float* __restrict__ out) {
    const int wid = (blockIdx.x * blockDim.x + threadIdx.x) >> 6;  // [0, 16384)
    const int lane = threadIdx.x & 63;
    const int b = wid >> 10;      // [0,16)
    const int h = wid & 1023;     // [0,1024)
    const float4* xr = (const float4*)(xsum + (size_t)b * H);
    const float4* wr = (const float4*)(Wv + (size_t)h * H);
    float acc = 0.f;
#pragma unroll
    for (int it = 0; it < 4; ++it) {
        const int j4 = lane + it * 64;          // 256 float4 per row
        float4 xv = xr[j4];
        float4 wv = wr[j4];
        acc += xv.x * wv.x + xv.y * wv.y + xv.z * wv.z + xv.w * wv.w;
    }
#pragma unroll
    for (int off = 32; off > 0; off >>= 1) acc += __shfl_down(acc, off, 64);
    if (lane == 0) {
        const int c = b * H + h;
        out[c] = (xsum[c] + acc) * (1.0f / (float)S) + bv[h];
    }
}

extern "C" void kernel_launch(void* const* d_in, const int* in_sizes, int n_in,
                              void* d_out, int out_size, void* d_ws, size_t ws_size,
                              hipStream_t stream) {
    const float* x  = (const float*)d_in[0];
    // d_in[1]=Wq, d_in[2]=bq, d_in[3]=Wk, d_in[4]=bk are provably unused (see header).
    const float* Wv = (const float*)d_in[5];
    const float* bv = (const float*)d_in[6];
    float* out = (float*)d_out;
    float* ws  = (float*)d_ws;

    const size_t needA = (size_t)(SPLITS + 1) * C * sizeof(float);  // ~2.1 MiB
    if (ws_size >= needA) {
        float* part = ws;                       // [SPLITS][C]
        float* xsum = ws + (size_t)SPLITS * C;  // [C]
        k_colsum<<<dim3(C / 4 / 256, SPLITS), 256, 0, stream>>>(
            (const float4*)x, (float4*)part);
        k_reduce<<<C / 256, 256, 0, stream>>>(part, xsum);
        k_out<<<16384 / 4, 256, 0, stream>>>(xsum, Wv, bv, out);
    } else {
        // Fallback: atomic accumulation directly into ws[0..C).
        hipMemsetAsync(d_ws, 0, (size_t)C * sizeof(float), stream);
        k_colsum_atomic<<<dim3(C / 256, SPLITS), 256, 0, stream>>>(x, ws);
        k_out<<<16384 / 4, 256, 0, stream>>>(ws, Wv, bv, out);
    }
}